// Round 1
// 164.521 us; speedup vs baseline: 1.0377x; 1.0377x over previous
//
#include <hip/hip_runtime.h>

#define IN_FEAT    128
#define EDGE_EMBED 32
// W1_w: [256, 256] row-major. W2_w: [2, 288] row-major.
//
// Factorization (no nonlinearity anywhere):
//   score[i,j] = pu[src[i]][j] + pv[dst[i]][j] + sum_m e[i,m]*W2_w[j,256+m] + bias[j]
//   pu[n][j] = sum_{f<128} h[n,f]   * M[f,j]
//   pv[n][j] = sum_{f<128} h[n,f]   * M[128+f,j]
//   M[f,j]   = sum_k W1_w[k,f] * W2_w[j,k]
//   bias[j]  = sum_k W1_b[k]   * W2_w[j,k] + W2_b[j]
//
// ws layout (floats):
//   [0..511]      M[f*2+j]
//   [512..513]    bias
//   [1024 ..]     pu[n*2+j]   (N*2 floats)
//   [1024+2N ..]  pv[n*2+j]   (N*2 floats)    total < 1 MB

// ---------------------------------------------------------------------------
// Kernel A (R2): parallelized across 8 workgroups. Previous version was one
// workgroup with a 256-deep k-chain on cold HBM (~8-12 us, serialized in
// front of B and C). Now: block b owns f in [32b, 32b+32); the k-sum is
// split 8x across thread groups (kg = tid>>5, 32 k's each), reduced with
// one shfl_xor(32) + a 4-wave LDS pass. Every block writes a disjoint
// slice of M -> no atomics, no zero-init of the poisoned workspace.
// ---------------------------------------------------------------------------
__global__ __launch_bounds__(256) void precompute_kernel(
    const float* __restrict__ W1_w, const float* __restrict__ W1_b,
    const float* __restrict__ W2_w, const float* __restrict__ W2_b,
    float* __restrict__ ws) {
    __shared__ float red[4][32][2];
    const int tid = threadIdx.x;
    const int fl  = tid & 31;            // f within this block's chunk
    const int kg  = tid >> 5;            // 0..7: k-slice
    const int f   = blockIdx.x * 32 + fl;

    float m0 = 0.f, m1 = 0.f;
#pragma unroll
    for (int i = 0; i < 32; ++i) {
        const int k = kg * 32 + i;
        const float w1 = W1_w[k * 256 + f];   // 2x128B segments per wave-load
        m0 = fmaf(w1, W2_w[k], m0);
        m1 = fmaf(w1, W2_w[288 + k], m1);
    }
    // kg bit0 == lane bit5: one butterfly folds kg pairs within the wave
    m0 += __shfl_xor(m0, 32);
    m1 += __shfl_xor(m1, 32);
    const int w = tid >> 6;
    if ((tid & 63) < 32) { red[w][fl][0] = m0; red[w][fl][1] = m1; }
    __syncthreads();

    if (tid < 32) {                      // fold the 4 waves, write M slice
        const float a0 = red[0][tid][0] + red[1][tid][0] + red[2][tid][0] + red[3][tid][0];
        const float a1 = red[0][tid][1] + red[1][tid][1] + red[2][tid][1] + red[3][tid][1];
        ws[(blockIdx.x * 32 + tid) * 2 + 0] = a0;
        ws[(blockIdx.x * 32 + tid) * 2 + 1] = a1;
    }

    // bias: wave 1 of block 0 (independent of the reduce above)
    if (blockIdx.x == 0 && tid >= 64 && tid < 128) {
        const int t = tid - 64;
        float b0 = 0.f, b1 = 0.f;
#pragma unroll
        for (int m = 0; m < 4; ++m) {
            const int k = t + 64 * m;
            const float wb = W1_b[k];
            b0 = fmaf(wb, W2_w[k], b0);
            b1 = fmaf(wb, W2_w[288 + k], b1);
        }
#pragma unroll
        for (int m = 32; m >= 1; m >>= 1) {
            b0 += __shfl_xor(b0, m);
            b1 += __shfl_xor(b1, m);
        }
        if (t == 0) {
            ws[512] = b0 + W2_b[0];
            ws[513] = b1 + W2_b[1];
        }
    }
}

// ---------------------------------------------------------------------------
// Kernel B: per-node projections. 32 lanes per node row (one float4/lane
// covers the 512 B row in one coalesced instruction); 4 accumulators;
// 5-step shuffle reduce (masks <=16 stay inside each 32-lane half).
// Reads h exactly once: 25.6 MB -> ~5 us.
// ---------------------------------------------------------------------------
__global__ __launch_bounds__(256, 8) void node_proj_kernel(
    const float* __restrict__ h, const float* __restrict__ ws,
    float* __restrict__ pu, float* __restrict__ pv, int N) {
    const int p = threadIdx.x & 31;
    const int node = blockIdx.x * 8 + (threadIdx.x >> 5);
    if (node >= N) return;

    const float4 muA = *(const float4*)(ws + p * 8);
    const float4 muB = *(const float4*)(ws + p * 8 + 4);
    const float4 mvA = *(const float4*)(ws + 256 + p * 8);
    const float4 mvB = *(const float4*)(ws + 256 + p * 8 + 4);

    const float4 hr = *(const float4*)(h + (size_t)node * IN_FEAT + p * 4);

    float u0 = hr.x * muA.x, u1 = hr.x * muA.y;
    u0 = fmaf(hr.y, muA.z, u0); u1 = fmaf(hr.y, muA.w, u1);
    u0 = fmaf(hr.z, muB.x, u0); u1 = fmaf(hr.z, muB.y, u1);
    u0 = fmaf(hr.w, muB.z, u0); u1 = fmaf(hr.w, muB.w, u1);
    float v0 = hr.x * mvA.x, v1 = hr.x * mvA.y;
    v0 = fmaf(hr.y, mvA.z, v0); v1 = fmaf(hr.y, mvA.w, v1);
    v0 = fmaf(hr.z, mvB.x, v0); v1 = fmaf(hr.z, mvB.y, v1);
    v0 = fmaf(hr.w, mvB.z, v0); v1 = fmaf(hr.w, mvB.w, v1);

#pragma unroll
    for (int m = 16; m >= 1; m >>= 1) {
        u0 += __shfl_xor(u0, m); u1 += __shfl_xor(u1, m);
        v0 += __shfl_xor(v0, m); v1 += __shfl_xor(v1, m);
    }
    if (p == 0) {
        *(float2*)(pu + (size_t)node * 2) = make_float2(u0, u1);
        *(float2*)(pv + (size_t)node * 2) = make_float2(v0, v1);
    }
}

// ---------------------------------------------------------------------------
// Kernel C: edge scores. 8 lanes per edge: lane p covers e[edge*32+p*4..+3]
// (one float4; 8-lane group = 128 B contiguous, wave = 1 KB contiguous).
// Lane 0 gathers pu[src] (8 B), lane 4 gathers pv[dst] — both tables are
// 400 KB, L2-resident on every XCD. 3-step shuffle reduce over 8 lanes.
// ---------------------------------------------------------------------------
__global__ __launch_bounds__(256, 8) void edge_score_kernel(
    const int* __restrict__ src, const int* __restrict__ dst,
    const float* __restrict__ e, const float* __restrict__ W2_w,
    const float* __restrict__ ws, const float* __restrict__ pu,
    const float* __restrict__ pv, float* __restrict__ out,
    int E, int numGroups) {
    const int p = threadIdx.x & 7;
    int group = blockIdx.x * (blockDim.x >> 3) + (threadIdx.x >> 3);

    // e-part weights for this lane's 4 embed dims
    const float4 w0 = *(const float4*)(W2_w + 256 + p * 4);        // j=0
    const float4 w1 = *(const float4*)(W2_w + 544 + p * 4);        // j=1
    const float b0 = ws[512], b1 = ws[513];

    for (int edge = group; edge < E; edge += numGroups) {
        const float4 ev = *(const float4*)(e + (size_t)edge * EDGE_EMBED + p * 4);

        float acc0 = ev.x * w0.x;
        float acc1 = ev.x * w1.x;
        acc0 = fmaf(ev.y, w0.y, acc0); acc1 = fmaf(ev.y, w1.y, acc1);
        acc0 = fmaf(ev.z, w0.z, acc0); acc1 = fmaf(ev.z, w1.z, acc1);
        acc0 = fmaf(ev.w, w0.w, acc0); acc1 = fmaf(ev.w, w1.w, acc1);

        if (p == 0) {                       // src endpoint projection
            const int s = src[edge];
            const float2 u = *(const float2*)(pu + (size_t)s * 2);
            acc0 += u.x; acc1 += u.y;
        } else if (p == 4) {                // dst endpoint projection
            const int d = dst[edge];
            const float2 v = *(const float2*)(pv + (size_t)d * 2);
            acc0 += v.x; acc1 += v.y;
        }

#pragma unroll
        for (int m = 4; m >= 1; m >>= 1) {  // masks 4,2,1: stay in 8-lane group
            acc0 += __shfl_xor(acc0, m);
            acc1 += __shfl_xor(acc1, m);
        }
        if (p == 0) {
            *(float2*)(out + (size_t)edge * 2) = make_float2(acc0 + b0, acc1 + b1);
        }
    }
}

extern "C" void kernel_launch(void* const* d_in, const int* in_sizes, int n_in,
                              void* d_out, int out_size, void* d_ws, size_t ws_size,
                              hipStream_t stream) {
    const float* h    = (const float*)d_in[0];
    const int*   src  = (const int*)d_in[1];
    const int*   dst  = (const int*)d_in[2];
    const float* e    = (const float*)d_in[3];
    const float* W1_w = (const float*)d_in[4];
    const float* W1_b = (const float*)d_in[5];
    const float* W2_w = (const float*)d_in[6];
    const float* W2_b = (const float*)d_in[7];
    float* out = (float*)d_out;
    float* ws  = (float*)d_ws;

    const int E = in_sizes[1];
    const int N = in_sizes[0] / IN_FEAT;

    float* pu = ws + 1024;
    float* pv = ws + 1024 + (size_t)N * 2;

    precompute_kernel<<<8, 256, 0, stream>>>(W1_w, W1_b, W2_w, W2_b, ws);
    node_proj_kernel<<<(N + 7) / 8, 256, 0, stream>>>(h, ws, pu, pv, N);

    const int BLOCKS = 2048;               // 8 blocks/CU resident
    const int numGroups = BLOCKS * (256 / 8);
    edge_score_kernel<<<BLOCKS, 256, 0, stream>>>(src, dst, e, W2_w, ws, pu, pv,
                                                  out, E, numGroups);
}